// Round 1
// baseline (74.003 us; speedup 1.0000x reference)
//
#include <hip/hip_runtime.h>

#define N_CELLS 320
#define TSTEPS  324   // 322 wavefront steps, padded to a multiple of 4

__device__ __forceinline__ float fexp2(float x) {
  float r; asm("v_exp_f32 %0, %1" : "=v"(r) : "v"(x)); return r;
}
__device__ __forceinline__ float frcp(float x) {
  float r; asm("v_rcp_f32 %0, %1" : "=v"(r) : "v"(x)); return r;
}
__device__ __forceinline__ float bperm(int idx_bytes, float v) {
  return __int_as_float(__builtin_amdgcn_ds_bpermute(idx_bytes, __float_as_int(v)));
}
template <int SEL>
__device__ __forceinline__ float qbcast(float v) {
  // quad_perm broadcast: every lane in a quad reads quad-slot SEL (VALU-speed DPP)
  return __int_as_float(
      __builtin_amdgcn_mov_dpp(__float_as_int(v), SEL * 0x55, 0xF, 0xF, true));
}

__global__ __launch_bounds__(64, 1) void lstm_chain_kernel(
    const float* __restrict__ state,
    const float* __restrict__ w_ih0,
    const float* __restrict__ w_ih12,
    const float* __restrict__ w_hh,
    const float* __restrict__ b_ih,
    const float* __restrict__ b_hh,
    float* __restrict__ out) {
  __shared__ float slog[N_CELLS * 3];

  const int lane = threadIdx.x;
  const int row  = lane >> 4;   // 0..2 = layer, 3 = dummy
  const int col  = lane & 15;
  const int quad = col >> 2;    // 0..2 = hidden unit j, 3 = dummy (replicates j=2)
  const int tsl  = col & 3;     // 0:i 1:f 2:g 3:o
  const int lc   = row < 2 ? row : 2;
  const int jc   = quad < 2 ? quad : 2;
  const int g    = tsl * 3 + jc;  // gate row in [G=12] weight matrices

  const float LOG2E = 1.4426950408889634f;
  // unified activation: a = exp2(sact*x); d = rcp(1+a); act = d*mact + nact
  const float sact = (tsl == 2) ? 2.0f * LOG2E : -LOG2E;  // tanh vs sigmoid
  const float mact = (tsl == 2) ? -2.0f : 1.0f;
  const float nact = (tsl == 2) ? 1.0f : 0.0f;

  // byte-offset addressing constants (per-lane, loop-invariant)
  const int strideWi = (row == 0) ? 48 : 288;
  const int kWi = (row == 0) ? g * 4 : ((lc - 1) * 12 + g) * 12;
  const int kWh = (lc * 12 + g) * 12;
  const int kB  = (lc * 12 + g) * 4;
  const char* wiBase = (row == 0) ? (const char*)w_ih0 : (const char*)w_ih12;
  const char* whBase = (const char*)w_hh;
  const char* biBase = (const char*)b_ih;
  const char* bhBase = (const char*)b_hh;

  // bpermute lane indices (bytes), loop-invariant
  const int ix0 = ((row - 1) * 16 + 0 * 4 + tsl) * 4;  // x = h of layer below
  const int ix1 = ((row - 1) * 16 + 1 * 4 + tsl) * 4;
  const int ix2 = ((row - 1) * 16 + 2 * 4 + tsl) * 4;
  const int ih0 = (row * 16 + 0 * 4 + tsl) * 4;        // own-layer h broadcast
  const int ih1 = (row * 16 + 1 * 4 + tsl) * 4;
  const int ih2 = (row * 16 + 2 * 4 + tsl) * 4;

  const bool isRow0  = (row == 0);
  const bool outLane = (row == 2) && (tsl == 0) && (quad < 3);

  float h = 0.0f, c = 0.0f;  // torch zero initial carry (cell 0)

  float Wi0[4], Wi1[4], Wi2[4], Wh0[4], Wh1[4], Wh2[4], Bs[4], St[4];

  auto prefetch = [&](int tstep, int u) {
    int ip = tstep - row;                       // cell this row handles at tstep
    ip = ip < 0 ? 0 : (ip > N_CELLS - 1 ? N_CELLS - 1 : ip);  // clamp (garbage-safe)
    const int offWi = ip * strideWi + kWi;
    const int offWh = ip * 432 + kWh;
    const int offB  = ip * 144 + kB;
    float a0 = *(const float*)(wiBase + offWi);
    float a1 = *(const float*)(wiBase + offWi + 4);
    float a2 = *(const float*)(wiBase + offWi + 8);
    Wi0[u] = a0;
    Wi1[u] = isRow0 ? 0.0f : a1;  // sanitize: row0 x1/x2 are zero; avoid NaN*0
    Wi2[u] = isRow0 ? 0.0f : a2;
    Wh0[u] = *(const float*)(whBase + offWh);
    Wh1[u] = *(const float*)(whBase + offWh + 4);
    Wh2[u] = *(const float*)(whBase + offWh + 8);
    Bs[u]  = *(const float*)(biBase + offB) + *(const float*)(bhBase + offB);
    int si = tstep > N_CELLS - 1 ? N_CELLS - 1 : tstep;
    St[u]  = state[si];
  };

  auto stepf = [&](int t, int u) {
    // gather: x from layer below, p = own-layer previous-cell h (all from prev step)
    float x0 = bperm(ix0, h), x1 = bperm(ix1, h), x2 = bperm(ix2, h);
    float p0 = bperm(ih0, h), p1 = bperm(ih1, h), p2 = bperm(ih2, h);
    x0 = isRow0 ? St[u] : x0;
    x1 = isRow0 ? 0.0f : x1;
    x2 = isRow0 ? 0.0f : x2;
    float gate = Bs[u] + Wi0[u] * x0 + Wi1[u] * x1 + Wi2[u] * x2 +
                 Wh0[u] * p0 + Wh1[u] * p1 + Wh2[u] * p2;
    float a   = fexp2(gate * sact);
    float d   = frcp(1.0f + a);
    float act = fmaf(d, mact, nact);           // sigmoid or tanh, no divergence
    float vi = qbcast<0>(act);
    float vf = qbcast<1>(act);
    float vg = qbcast<2>(act);
    float vo = qbcast<3>(act);
    float cn  = fmaf(vf, c, vi * vg);
    float a2c = fexp2(cn * (2.0f * LOG2E));
    float th  = fmaf(frcp(1.0f + a2c), -2.0f, 1.0f);  // tanh(cn)
    float hn  = vo * th;
    bool valid = (row < 3) && (t >= row) && ((t - row) < N_CELLS);
    h = valid ? hn : h;
    c = valid ? cn : c;
    if (outLane && valid) slog[(t - 2) * 3 + quad] = hn;  // raw top-layer h
  };

#pragma unroll
  for (int u = 0; u < 4; ++u) prefetch(u, u);

  for (int t = 0; t < TSTEPS; t += 4) {
#pragma unroll
    for (int u = 0; u < 4; ++u) {
      stepf(t + u, u);
      prefetch(t + u + 4, u);  // refill bank for step t+u+4 (depth-4 pipeline)
    }
  }

  __syncthreads();

  // parallel softmax epilogue over all 320 cells
  for (int ci = lane; ci < N_CELLS; ci += 64) {
    float a0 = slog[ci * 3 + 0];
    float a1 = slog[ci * 3 + 1];
    float a2 = slog[ci * 3 + 2];
    float m  = fmaxf(fmaxf(a0, a1), a2);
    float e0 = fexp2((a0 - m) * LOG2E);
    float e1 = fexp2((a1 - m) * LOG2E);
    float e2 = fexp2((a2 - m) * LOG2E);
    float inv = frcp(e0 + e1 + e2);
    out[ci * 3 + 0] = e0 * inv;
    out[ci * 3 + 1] = e1 * inv;
    out[ci * 3 + 2] = e2 * inv;
  }
}

extern "C" void kernel_launch(void* const* d_in, const int* in_sizes, int n_in,
                              void* d_out, int out_size, void* d_ws, size_t ws_size,
                              hipStream_t stream) {
  const float* state  = (const float*)d_in[0];
  const float* w_ih0  = (const float*)d_in[1];
  const float* w_ih12 = (const float*)d_in[2];
  const float* w_hh   = (const float*)d_in[3];
  const float* b_ih   = (const float*)d_in[4];
  const float* b_hh   = (const float*)d_in[5];
  float* out = (float*)d_out;
  hipLaunchKernelGGL(lstm_chain_kernel, dim3(1), dim3(64), 0, stream,
                     state, w_ih0, w_ih12, w_hh, b_ih, b_hh, out);
}

// Round 2
// 46.829 us; speedup vs baseline: 1.5803x; 1.5803x over previous
//
#include <hip/hip_runtime.h>

#define NC      320
#define TSTEPS  324   // 322 wavefront steps, padded to multiple of 6
#define TS_PAD  336   // staged steps (covers prefetch overrun), mult of 6

typedef __attribute__((ext_vector_type(2))) unsigned int uint2v;

struct __align__(16) Bank { float4 a; float4 b; float2 c; };
// a = Wi'_0..3 (pre-permuted input weights), b = Wh'_0..3, c = {bias_sum, state}

__device__ __forceinline__ float fexp2(float x) {
  float r; asm("v_exp_f32 %0, %1" : "=v"(r) : "v"(x)); return r;
}
__device__ __forceinline__ float frcp(float x) {
  float r; asm("v_rcp_f32 %0, %1" : "=v"(r) : "v"(x)); return r;
}
template <int SEL>
__device__ __forceinline__ float qb(float v) {  // quad broadcast slot SEL
  return __int_as_float(
      __builtin_amdgcn_mov_dpp(__float_as_int(v), SEL * 0x55, 0xF, 0xF, true));
}
template <int CTRL>
__device__ __forceinline__ float rorf(float v) {  // row_ror:N DPP
  return __int_as_float(
      __builtin_amdgcn_mov_dpp(__float_as_int(v), CTRL, 0xF, 0xF, true));
}
__device__ __forceinline__ float bperm(int idx_bytes, float v) {
  return __int_as_float(__builtin_amdgcn_ds_bpermute(idx_bytes, __float_as_int(v)));
}

// ---------------- staging kernel: gather weights into per-(step,lane) stream --
__global__ void stage_kernel(const float* __restrict__ state,
                             const float* __restrict__ w_ih0,
                             const float* __restrict__ w_ih12,
                             const float* __restrict__ w_hh,
                             const float* __restrict__ b_ih,
                             const float* __restrict__ b_hh,
                             Bank* __restrict__ ws) {
  int idx = blockIdx.x * 256 + threadIdx.x;   // grid covers TS_PAD*64 exactly
  int t = idx >> 6, lane = idx & 63;
  int row = lane >> 4, quad = (lane >> 2) & 3, tsl = lane & 3;
  int i = t - row;                            // cell this row handles at step t
  int g = tsl * 3 + (quad < 3 ? quad : 0);    // gate row (quad3: dummy, unused)
  float wi[4] = {0.f, 0.f, 0.f, 0.f}, wh[4] = {0.f, 0.f, 0.f, 0.f};
  float bias = 0.f;
  bool valid = (row < 3) && (quad < 3) && (i >= 0) && (i < NC);
  if (valid) {
    if (row == 0) {
      wi[0] = w_ih0[i * 12 + g];              // input_size=1; x = state scalar
    } else {
      const float* base = w_ih12 + ((size_t)(i * 2 + (row - 1)) * 12 + g) * 3;
#pragma unroll
      for (int k = 0; k < 4; ++k) {           // q_k = quad delivered by ror:4k
        int qk = (quad - k) & 3;
        if (qk < 3) wi[k] = base[qk];
      }
    }
    const float* hb = w_hh + ((size_t)(i * 3 + row) * 12 + g) * 3;
#pragma unroll
    for (int k = 0; k < 4; ++k) {
      int qk = (quad - k) & 3;
      if (qk < 3) wh[k] = hb[qk];
    }
    bias = b_ih[(i * 3 + row) * 12 + g] + b_hh[(i * 3 + row) * 12 + g];
  }
  Bank bk;
  bk.a.x = wi[0]; bk.a.y = wi[1]; bk.a.z = wi[2]; bk.a.w = wi[3];
  bk.b.x = wh[0]; bk.b.y = wh[1]; bk.b.z = wh[2]; bk.b.w = wh[3];
  bk.c.x = bias;
  bk.c.y = (t < NC) ? state[t] : 0.f;         // row0's x at step t
  ws[(size_t)t * 64 + lane] = bk;
}

// ---------------- main chain kernel: 1 wave, permlane/DPP cross-lane ---------
__global__ __launch_bounds__(64, 1) void lstm_fast(const Bank* __restrict__ ws,
                                                   float* __restrict__ out) {
  __shared__ float slog[2048];  // 8 KB: [0,3888) = h stream, [3904,..) = dump

  const int lane = threadIdx.x;
  const int row  = lane >> 4;     // 0..2 layer, 3 dummy
  const int quad = (lane >> 2) & 3;
  const int tsl  = lane & 3;      // 0:i 1:f 2:g 3:o

  const float LOG2E = 1.4426950408889634f;
  const float sact = (tsl == 2) ? 2.0f * LOG2E : -LOG2E;
  const float mact = (tsl == 2) ? -2.0f : 1.0f;
  const float nact = (tsl == 2) ? 1.0f : 0.0f;

  const bool isRow0 = (row == 0);
  const bool isRow2 = (row == 2);
  const bool outLane = isRow2 && (tsl == 0) && (quad < 3);

  int sAddr = outLane ? quad * 4 : (3904 + lane * 4);  // byte addr into slog

  const Bank* pf0 = ws + lane;
  float4 wa[6], wb[6];
  float2 wc[6];
  float h = 0.f, c = 0.f;

#pragma unroll
  for (int u = 0; u < 6; ++u) {
    Bank bk = pf0[(size_t)u * 64];
    wa[u] = bk.a; wb[u] = bk.b; wc[u] = bk.c;
  }

  for (int t = 0; t < TSTEPS; t += 6) {
#pragma unroll
    for (int u = 0; u < 6; ++u) {
      // ---- cross-row shift: X = h of layer below (row0: state) ----
      unsigned hv = __float_as_uint(h);
      uint2v s16 = __builtin_amdgcn_permlane16_swap(hv, hv, false, false);
      // s16.x rows = [h0,h0,h2,h2], s16.y rows = [h1,h1,h3,h3]
      uint2v s32 = __builtin_amdgcn_permlane32_swap(s16.y, s16.y, false, false);
      // s32.x rows = [h1,h1,h1,h1]
      float A = __uint_as_float(s16.x);
      float E = __uint_as_float(s32.x);
      float T1 = isRow0 ? wc[u].y : A;   // row0 <- state, row1 <- h0 (row3 dc)
      float X  = isRow2 ? E : T1;        // row2 <- h1
      // ---- quad gathers via row rotations (weights pre-permuted) ----
      float X1 = rorf<0x124>(X), X2 = rorf<0x128>(X), X3 = rorf<0x12C>(X);
      float H1 = rorf<0x124>(h), H2 = rorf<0x128>(h), H3 = rorf<0x12C>(h);
      // ---- gate = b + Wi'.Xrots + Wh'.Hrots ----
      float cAcc = fmaf(wb[u].x, h,  wc[u].x);
      cAcc       = fmaf(wb[u].y, H1, cAcc);
      cAcc       = fmaf(wb[u].z, H2, cAcc);
      cAcc       = fmaf(wb[u].w, H3, cAcc);
      float m01  = fmaf(wa[u].y, X1, wa[u].x * X);
      float m23  = fmaf(wa[u].w, X3, wa[u].z * X2);
      float gate = cAcc + (m01 + m23);
      // ---- unified activation (sigmoid / tanh, no divergence) ----
      float aa  = fexp2(gate * sact);
      float dd  = frcp(1.0f + aa);
      float act = fmaf(dd, mact, nact);
      float vi = qb<0>(act), vf = qb<1>(act), vg = qb<2>(act), vo = qb<3>(act);
      float cn = fmaf(vf, c, vi * vg);
      float a2 = fexp2(cn * (2.0f * LOG2E));
      float th = fmaf(frcp(1.0f + a2), -2.0f, 1.0f);
      h = vo * th;
      c = cn;
      // zero-staged weights make invalid/dummy lanes hold h=c=0 exactly:
      // no valid-masking needed, and cell 0 sees the correct zero carry.
      *(float*)((char*)slog + sAddr + u * 12) = h;
      // ---- refill bank u for step t+u+6 ----
      Bank bk = pf0[(size_t)(t + u + 6) * 64];
      wa[u] = bk.a; wb[u] = bk.b; wc[u] = bk.c;
    }
    sAddr += 72;
  }

  __syncthreads();

  for (int ci = lane; ci < NC; ci += 64) {
    int s = (ci + 2) * 3;   // cell ci was stored at step ci+2
    float a0 = slog[s], a1 = slog[s + 1], a2v = slog[s + 2];
    float mx = fmaxf(fmaxf(a0, a1), a2v);
    float e0 = fexp2((a0 - mx) * LOG2E);
    float e1 = fexp2((a1 - mx) * LOG2E);
    float e2 = fexp2((a2v - mx) * LOG2E);
    float inv = frcp(e0 + e1 + e2);
    out[ci * 3 + 0] = e0 * inv;
    out[ci * 3 + 1] = e1 * inv;
    out[ci * 3 + 2] = e2 * inv;
  }
}

// ---------------- fallback: proven R1 kernel (used if ws too small) ----------
__global__ __launch_bounds__(64, 1) void lstm_chain_fb(
    const float* __restrict__ state, const float* __restrict__ w_ih0,
    const float* __restrict__ w_ih12, const float* __restrict__ w_hh,
    const float* __restrict__ b_ih, const float* __restrict__ b_hh,
    float* __restrict__ out) {
  __shared__ float slog[NC * 3];
  const int lane = threadIdx.x;
  const int row = lane >> 4, col = lane & 15, quad = col >> 2, tsl = col & 3;
  const int lc = row < 2 ? row : 2, jc = quad < 2 ? quad : 2;
  const int g = tsl * 3 + jc;
  const float LOG2E = 1.4426950408889634f;
  const float sact = (tsl == 2) ? 2.0f * LOG2E : -LOG2E;
  const float mact = (tsl == 2) ? -2.0f : 1.0f;
  const float nact = (tsl == 2) ? 1.0f : 0.0f;
  const int strideWi = (row == 0) ? 48 : 288;
  const int kWi = (row == 0) ? g * 4 : ((lc - 1) * 12 + g) * 12;
  const int kWh = (lc * 12 + g) * 12, kB = (lc * 12 + g) * 4;
  const char* wiBase = (row == 0) ? (const char*)w_ih0 : (const char*)w_ih12;
  const int ix0 = ((row - 1) * 16 + 0 + tsl) * 4, ix1 = ((row - 1) * 16 + 4 + tsl) * 4,
            ix2 = ((row - 1) * 16 + 8 + tsl) * 4;
  const int ih0 = (row * 16 + 0 + tsl) * 4, ih1 = (row * 16 + 4 + tsl) * 4,
            ih2 = (row * 16 + 8 + tsl) * 4;
  const bool isRow0 = (row == 0);
  const bool outLane = (row == 2) && (tsl == 0) && (quad < 3);
  float h = 0.f, c = 0.f;
  float Wi0[4], Wi1[4], Wi2[4], Wh0[4], Wh1[4], Wh2[4], Bs[4], St[4];
  auto prefetch = [&](int ts, int u) {
    int ip = ts - row; ip = ip < 0 ? 0 : (ip > NC - 1 ? NC - 1 : ip);
    const int oWi = ip * strideWi + kWi, oWh = ip * 432 + kWh, oB = ip * 144 + kB;
    float a0 = *(const float*)(wiBase + oWi);
    float a1 = *(const float*)(wiBase + oWi + 4);
    float a2 = *(const float*)(wiBase + oWi + 8);
    Wi0[u] = a0; Wi1[u] = isRow0 ? 0.f : a1; Wi2[u] = isRow0 ? 0.f : a2;
    Wh0[u] = *(const float*)((const char*)w_hh + oWh);
    Wh1[u] = *(const float*)((const char*)w_hh + oWh + 4);
    Wh2[u] = *(const float*)((const char*)w_hh + oWh + 8);
    Bs[u] = *(const float*)((const char*)b_ih + oB) + *(const float*)((const char*)b_hh + oB);
    int si = ts > NC - 1 ? NC - 1 : ts;
    St[u] = state[si];
  };
  auto stepf = [&](int t, int u) {
    float x0 = bperm(ix0, h), x1 = bperm(ix1, h), x2 = bperm(ix2, h);
    float p0 = bperm(ih0, h), p1 = bperm(ih1, h), p2 = bperm(ih2, h);
    x0 = isRow0 ? St[u] : x0; x1 = isRow0 ? 0.f : x1; x2 = isRow0 ? 0.f : x2;
    float gate = Bs[u] + Wi0[u] * x0 + Wi1[u] * x1 + Wi2[u] * x2 +
                 Wh0[u] * p0 + Wh1[u] * p1 + Wh2[u] * p2;
    float aa = fexp2(gate * sact);
    float act = fmaf(frcp(1.0f + aa), mact, nact);
    float vi = qb<0>(act), vf = qb<1>(act), vg = qb<2>(act), vo = qb<3>(act);
    float cn = fmaf(vf, c, vi * vg);
    float a2c = fexp2(cn * (2.0f * LOG2E));
    float th = fmaf(frcp(1.0f + a2c), -2.0f, 1.0f);
    float hn = vo * th;
    bool valid = (row < 3) && (t >= row) && ((t - row) < NC);
    h = valid ? hn : h; c = valid ? cn : c;
    if (outLane && valid) slog[(t - 2) * 3 + quad] = hn;
  };
#pragma unroll
  for (int u = 0; u < 4; ++u) prefetch(u, u);
  for (int t = 0; t < TSTEPS; t += 4) {
#pragma unroll
    for (int u = 0; u < 4; ++u) { stepf(t + u, u); prefetch(t + u + 4, u); }
  }
  __syncthreads();
  for (int ci = lane; ci < NC; ci += 64) {
    float a0 = slog[ci * 3], a1 = slog[ci * 3 + 1], a2v = slog[ci * 3 + 2];
    float mx = fmaxf(fmaxf(a0, a1), a2v);
    float e0 = fexp2((a0 - mx) * LOG2E), e1 = fexp2((a1 - mx) * LOG2E),
          e2 = fexp2((a2v - mx) * LOG2E);
    float inv = frcp(e0 + e1 + e2);
    out[ci * 3 + 0] = e0 * inv; out[ci * 3 + 1] = e1 * inv; out[ci * 3 + 2] = e2 * inv;
  }
}

extern "C" void kernel_launch(void* const* d_in, const int* in_sizes, int n_in,
                              void* d_out, int out_size, void* d_ws, size_t ws_size,
                              hipStream_t stream) {
  const float* state  = (const float*)d_in[0];
  const float* w_ih0  = (const float*)d_in[1];
  const float* w_ih12 = (const float*)d_in[2];
  const float* w_hh   = (const float*)d_in[3];
  const float* b_ih   = (const float*)d_in[4];
  const float* b_hh   = (const float*)d_in[5];
  float* out = (float*)d_out;
  const size_t need = sizeof(Bank) * (size_t)TS_PAD * 64;  // ~1.01 MB
  if (ws_size >= need) {
    Bank* ws = (Bank*)d_ws;
    hipLaunchKernelGGL(stage_kernel, dim3(TS_PAD * 64 / 256), dim3(256), 0, stream,
                       state, w_ih0, w_ih12, w_hh, b_ih, b_hh, ws);
    hipLaunchKernelGGL(lstm_fast, dim3(1), dim3(64), 0, stream, ws, out);
  } else {
    hipLaunchKernelGGL(lstm_chain_fb, dim3(1), dim3(64), 0, stream,
                       state, w_ih0, w_ih12, w_hh, b_ih, b_hh, out);
  }
}

// Round 3
// 42.570 us; speedup vs baseline: 1.7384x; 1.1001x over previous
//
#include <hip/hip_runtime.h>

#define NC      320
#define TSTEPS  324   // 322 wavefront steps, padded to multiple of 6
#define TS_PAD  336   // staged steps (covers prefetch overrun), mult of 6

typedef __attribute__((ext_vector_type(2))) unsigned int uint2v;

struct __align__(16) Bank { float4 a; float4 b; float2 c; };
// a = wi'_0..3 (sact-prescaled, quad-pre-permuted; row0: zeros — state folded)
// b = wh'_0..3 (sact-prescaled, quad-pre-permuted)
// c = {bias' (sact-prescaled; row0 includes Wi*state[t]), pad}

__device__ __forceinline__ float fexp2(float x) {
  float r; asm("v_exp_f32 %0, %1" : "=v"(r) : "v"(x)); return r;
}
__device__ __forceinline__ float frcp(float x) {
  float r; asm("v_rcp_f32 %0, %1" : "=v"(r) : "v"(x)); return r;
}
template <int SEL>
__device__ __forceinline__ float qb(float v) {  // quad broadcast slot SEL
  return __int_as_float(
      __builtin_amdgcn_mov_dpp(__float_as_int(v), SEL * 0x55, 0xF, 0xF, true));
}
template <int CTRL>
__device__ __forceinline__ float rorf(float v) {  // row_ror:N DPP
  return __int_as_float(
      __builtin_amdgcn_mov_dpp(__float_as_int(v), CTRL, 0xF, 0xF, true));
}
__device__ __forceinline__ float bperm(int idx_bytes, float v) {
  return __int_as_float(__builtin_amdgcn_ds_bpermute(idx_bytes, __float_as_int(v)));
}

// ---------------- staging kernel -------------------------------------------
__global__ void stage_kernel(const float* __restrict__ state,
                             const float* __restrict__ w_ih0,
                             const float* __restrict__ w_ih12,
                             const float* __restrict__ w_hh,
                             const float* __restrict__ b_ih,
                             const float* __restrict__ b_hh,
                             Bank* __restrict__ ws) {
  int idx = blockIdx.x * 256 + threadIdx.x;   // grid covers TS_PAD*64 exactly
  int t = idx >> 6, lane = idx & 63;
  int row = lane >> 4, quad = (lane >> 2) & 3, tsl = lane & 3;
  int i = t - row;                            // cell this row handles at step t
  int g = tsl * 3 + (quad < 3 ? quad : 0);
  const float LOG2E = 1.4426950408889634f;
  const float sact = (tsl == 2) ? 2.0f * LOG2E : -LOG2E;
  float wi[4] = {0.f, 0.f, 0.f, 0.f}, wh[4] = {0.f, 0.f, 0.f, 0.f};
  float bias = 0.f;
  bool valid = (row < 3) && (quad < 3) && (i >= 0) && (i < NC);
  if (valid) {
    if (row == 0) {
      bias = w_ih0[i * 12 + g] * state[i];    // fold Wi*state into bias
    } else {
      const float* base = w_ih12 + ((size_t)(i * 2 + (row - 1)) * 12 + g) * 3;
#pragma unroll
      for (int k = 0; k < 4; ++k) {           // slot k feeds row_ror:4k source
        int qk = (quad - k) & 3;
        if (qk < 3) wi[k] = base[qk];
      }
    }
    const float* hb = w_hh + ((size_t)(i * 3 + row) * 12 + g) * 3;
#pragma unroll
    for (int k = 0; k < 4; ++k) {
      int qk = (quad - k) & 3;
      if (qk < 3) wh[k] = hb[qk];
    }
    bias += b_ih[(i * 3 + row) * 12 + g] + b_hh[(i * 3 + row) * 12 + g];
#pragma unroll
    for (int k = 0; k < 4; ++k) { wi[k] *= sact; wh[k] *= sact; }
    bias *= sact;                             // prescale: kills gate*sact mul
  }
  Bank bk;
  bk.a.x = wi[0]; bk.a.y = wi[1]; bk.a.z = wi[2]; bk.a.w = wi[3];
  bk.b.x = wh[0]; bk.b.y = wh[1]; bk.b.z = wh[2]; bk.b.w = wh[3];
  bk.c.x = bias;  bk.c.y = 0.f;
  ws[(size_t)t * 64 + lane] = bk;
}

// ---------------- main chain kernel: 1 wave --------------------------------
__global__ __launch_bounds__(64, 1) void lstm_fast(const Bank* __restrict__ ws,
                                                   float* __restrict__ out) {
  __shared__ float slog[2112];  // 8448 B: [0,3900) h stream, [4096,..) dump

  const int lane = threadIdx.x;
  const int row  = lane >> 4;     // 0:L0 1:L1 2:L2 3:dummy
  const int quad = (lane >> 2) & 3;
  const int tsl  = lane & 3;      // 0:i 1:f 2:g 3:o

  const float LOG2E = 1.4426950408889634f;
  const float mact = (tsl == 2) ? -2.0f : 1.0f;
  const float nact = (tsl == 2) ? 1.0f : 0.0f;
  const bool pickY = (lane >= 32) && (lane < 48);  // row2 takes y-result
  const bool outLane = (row == 2) && (tsl == 0) && (quad < 3);

  int sAddr = outLane ? quad * 4 : (4096 + lane * 4);  // byte addr into slog

  const Bank* pf0 = ws + lane;
  float4 wa[6], wb[6];
  float  bs[6];
  float h = 0.f, c = 0.f;

#pragma unroll
  for (int u = 0; u < 6; ++u) {
    Bank bk = pf0[(size_t)u * 64];
    wa[u] = bk.a; wb[u] = bk.b; bs[u] = bk.c.x;
  }

  for (int t = 0; t < TSTEPS; t += 6) {
#pragma unroll
    for (int u = 0; u < 6; ++u) {
      // ---- X route: rows [., h0, h1, .] via p32 -> p16swap -> 1 cndmask ----
      unsigned hv = __float_as_uint(h);
      uint2v p32 = __builtin_amdgcn_permlane32_swap(hv, hv, false, false);
      // p32.x rows = [h2, h3, h0, h1]
      uint2v s16 = __builtin_amdgcn_permlane16_swap(p32.x, hv, false, false);
      // s16.x rows = [h2, h0, h0, h2] ; s16.y rows = [h3, h1, h1, h3]
      float X = __uint_as_float(pickY ? s16.y : s16.x);
      // row0's X is garbage-but-finite: its wi are all zero (state folded).
      // ---- quad rotations (weights pre-permuted at staging) ----
      float H1 = rorf<0x124>(h), H2 = rorf<0x128>(h), H3 = rorf<0x12C>(h);
      float X1 = rorf<0x124>(X), X2 = rorf<0x128>(X), X3 = rorf<0x12C>(X);
      // ---- gate (pre-scaled by sact at staging) ----
      float cA  = fmaf(wb[u].y, H1, fmaf(wb[u].x, h, bs[u]));
      cA        = fmaf(wb[u].z, H2, cA);
      cA        = fmaf(wb[u].w, H3, cA);
      float m01 = fmaf(wa[u].y, X1, wa[u].x * X);
      float m23 = fmaf(wa[u].w, X3, wa[u].z * X2);
      float gate = (cA + m01) + m23;
      // ---- unified activation ----
      float aa  = fexp2(gate);
      float dd  = frcp(1.0f + aa);
      float act = fmaf(dd, mact, nact);
      float vi = qb<0>(act), vf = qb<1>(act), vg = qb<2>(act), vo = qb<3>(act);
      float nvo2 = -2.0f * vo;                 // off critical path
      float cn = fmaf(vf, c, vi * vg);
      float a2 = fexp2(cn * (2.0f * LOG2E));
      float d2 = frcp(1.0f + a2);
      h = fmaf(d2, nvo2, vo);                  // vo * tanh(cn), fused
      c = cn;
      // zero-staged weights keep invalid/dummy lanes at h=c=0 exactly.
      *(float*)((char*)slog + sAddr + u * 12) = h;
      // ---- refill bank u for step t+u+6 ----
      Bank bk = pf0[(size_t)(t + u + 6) * 64];
      wa[u] = bk.a; wb[u] = bk.b; bs[u] = bk.c.x;
    }
    sAddr += 72;
  }

  __syncthreads();

  for (int ci = lane; ci < NC; ci += 64) {
    int s = (ci + 2) * 3;   // cell ci was stored at step ci+2
    float a0 = slog[s], a1 = slog[s + 1], a2v = slog[s + 2];
    float mx = fmaxf(fmaxf(a0, a1), a2v);
    float e0 = fexp2((a0 - mx) * LOG2E);
    float e1 = fexp2((a1 - mx) * LOG2E);
    float e2 = fexp2((a2v - mx) * LOG2E);
    float inv = frcp(e0 + e1 + e2);
    out[ci * 3 + 0] = e0 * inv;
    out[ci * 3 + 1] = e1 * inv;
    out[ci * 3 + 2] = e2 * inv;
  }
}

// ---------------- fallback: proven R1 kernel (used if ws too small) ----------
__global__ __launch_bounds__(64, 1) void lstm_chain_fb(
    const float* __restrict__ state, const float* __restrict__ w_ih0,
    const float* __restrict__ w_ih12, const float* __restrict__ w_hh,
    const float* __restrict__ b_ih, const float* __restrict__ b_hh,
    float* __restrict__ out) {
  __shared__ float slog[NC * 3];
  const int lane = threadIdx.x;
  const int row = lane >> 4, col = lane & 15, quad = col >> 2, tsl = col & 3;
  const int lc = row < 2 ? row : 2, jc = quad < 2 ? quad : 2;
  const int g = tsl * 3 + jc;
  const float LOG2E = 1.4426950408889634f;
  const float sact = (tsl == 2) ? 2.0f * LOG2E : -LOG2E;
  const float mact = (tsl == 2) ? -2.0f : 1.0f;
  const float nact = (tsl == 2) ? 1.0f : 0.0f;
  const int strideWi = (row == 0) ? 48 : 288;
  const int kWi = (row == 0) ? g * 4 : ((lc - 1) * 12 + g) * 12;
  const int kWh = (lc * 12 + g) * 12, kB = (lc * 12 + g) * 4;
  const char* wiBase = (row == 0) ? (const char*)w_ih0 : (const char*)w_ih12;
  const int ix0 = ((row - 1) * 16 + 0 + tsl) * 4, ix1 = ((row - 1) * 16 + 4 + tsl) * 4,
            ix2 = ((row - 1) * 16 + 8 + tsl) * 4;
  const int ih0 = (row * 16 + 0 + tsl) * 4, ih1 = (row * 16 + 4 + tsl) * 4,
            ih2 = (row * 16 + 8 + tsl) * 4;
  const bool isRow0 = (row == 0);
  const bool outLane = (row == 2) && (tsl == 0) && (quad < 3);
  float h = 0.f, c = 0.f;
  float Wi0[4], Wi1[4], Wi2[4], Wh0[4], Wh1[4], Wh2[4], Bs[4], St[4];
  auto prefetch = [&](int ts, int u) {
    int ip = ts - row; ip = ip < 0 ? 0 : (ip > NC - 1 ? NC - 1 : ip);
    const int oWi = ip * strideWi + kWi, oWh = ip * 432 + kWh, oB = ip * 144 + kB;
    float a0 = *(const float*)(wiBase + oWi);
    float a1 = *(const float*)(wiBase + oWi + 4);
    float a2 = *(const float*)(wiBase + oWi + 8);
    Wi0[u] = a0; Wi1[u] = isRow0 ? 0.f : a1; Wi2[u] = isRow0 ? 0.f : a2;
    Wh0[u] = *(const float*)((const char*)w_hh + oWh);
    Wh1[u] = *(const float*)((const char*)w_hh + oWh + 4);
    Wh2[u] = *(const float*)((const char*)w_hh + oWh + 8);
    Bs[u] = *(const float*)((const char*)b_ih + oB) + *(const float*)((const char*)b_hh + oB);
    int si = ts > NC - 1 ? NC - 1 : ts;
    St[u] = state[si];
  };
  auto stepf = [&](int t, int u) {
    float x0 = bperm(ix0, h), x1 = bperm(ix1, h), x2 = bperm(ix2, h);
    float p0 = bperm(ih0, h), p1 = bperm(ih1, h), p2 = bperm(ih2, h);
    x0 = isRow0 ? St[u] : x0; x1 = isRow0 ? 0.f : x1; x2 = isRow0 ? 0.f : x2;
    float gate = Bs[u] + Wi0[u] * x0 + Wi1[u] * x1 + Wi2[u] * x2 +
                 Wh0[u] * p0 + Wh1[u] * p1 + Wh2[u] * p2;
    float aa = fexp2(gate * sact);
    float act = fmaf(frcp(1.0f + aa), mact, nact);
    float vi = qb<0>(act), vf = qb<1>(act), vg = qb<2>(act), vo = qb<3>(act);
    float cn = fmaf(vf, c, vi * vg);
    float a2c = fexp2(cn * (2.0f * LOG2E));
    float th = fmaf(frcp(1.0f + a2c), -2.0f, 1.0f);
    float hn = vo * th;
    bool valid = (row < 3) && (t >= row) && ((t - row) < NC);
    h = valid ? hn : h; c = valid ? cn : c;
    if (outLane && valid) slog[(t - 2) * 3 + quad] = hn;
  };
#pragma unroll
  for (int u = 0; u < 4; ++u) prefetch(u, u);
  for (int t = 0; t < TSTEPS; t += 4) {
#pragma unroll
    for (int u = 0; u < 4; ++u) { stepf(t + u, u); prefetch(t + u + 4, u); }
  }
  __syncthreads();
  for (int ci = lane; ci < NC; ci += 64) {
    float a0 = slog[ci * 3], a1 = slog[ci * 3 + 1], a2v = slog[ci * 3 + 2];
    float mx = fmaxf(fmaxf(a0, a1), a2v);
    float e0 = fexp2((a0 - mx) * LOG2E), e1 = fexp2((a1 - mx) * LOG2E),
          e2 = fexp2((a2v - mx) * LOG2E);
    float inv = frcp(e0 + e1 + e2);
    out[ci * 3 + 0] = e0 * inv; out[ci * 3 + 1] = e1 * inv; out[ci * 3 + 2] = e2 * inv;
  }
}

extern "C" void kernel_launch(void* const* d_in, const int* in_sizes, int n_in,
                              void* d_out, int out_size, void* d_ws, size_t ws_size,
                              hipStream_t stream) {
  const float* state  = (const float*)d_in[0];
  const float* w_ih0  = (const float*)d_in[1];
  const float* w_ih12 = (const float*)d_in[2];
  const float* w_hh   = (const float*)d_in[3];
  const float* b_ih   = (const float*)d_in[4];
  const float* b_hh   = (const float*)d_in[5];
  float* out = (float*)d_out;
  const size_t need = sizeof(Bank) * (size_t)TS_PAD * 64;  // ~1.03 MB
  if (ws_size >= need) {
    Bank* ws = (Bank*)d_ws;
    hipLaunchKernelGGL(stage_kernel, dim3(TS_PAD * 64 / 256), dim3(256), 0, stream,
                       state, w_ih0, w_ih12, w_hh, b_ih, b_hh, ws);
    hipLaunchKernelGGL(lstm_fast, dim3(1), dim3(64), 0, stream, ws, out);
  } else {
    hipLaunchKernelGGL(lstm_chain_fb, dim3(1), dim3(64), 0, stream,
                       state, w_ih0, w_ih12, w_hh, b_ih, b_hh, out);
  }
}

// Round 4
// 42.254 us; speedup vs baseline: 1.7514x; 1.0075x over previous
//
#include <hip/hip_runtime.h>

#define NC      320
#define TSTEPS  324   // 322 wavefront steps, padded to multiple of 6
#define TS_PAD  336   // staged steps (covers prefetch overrun), mult of 6

typedef __attribute__((ext_vector_type(2))) unsigned int uint2v;

struct __align__(16) Bank { float4 a; float4 b; float2 c; };
// a = wi'_0..3 (sact-prescaled, quad-pre-permuted; row0: zeros — state folded)
// b = wh'_0..3 (sact-prescaled, quad-pre-permuted)
// c = {bias' (sact-prescaled; row0 includes Wi*state[t]), pad}

__device__ __forceinline__ float fexp2(float x) { return __builtin_amdgcn_exp2f(x); }
__device__ __forceinline__ float frcp(float x)  { return __builtin_amdgcn_rcpf(x); }
template <int SEL>
__device__ __forceinline__ float qb(float v) {  // quad broadcast slot SEL
  return __int_as_float(
      __builtin_amdgcn_mov_dpp(__float_as_int(v), SEL * 0x55, 0xF, 0xF, true));
}
template <int CTRL>
__device__ __forceinline__ float rorf(float v) {  // row_ror:N DPP
  return __int_as_float(
      __builtin_amdgcn_mov_dpp(__float_as_int(v), CTRL, 0xF, 0xF, true));
}
__device__ __forceinline__ float bperm(int idx_bytes, float v) {
  return __int_as_float(__builtin_amdgcn_ds_bpermute(idx_bytes, __float_as_int(v)));
}

// ---------------- staging kernel -------------------------------------------
__global__ void stage_kernel(const float* __restrict__ state,
                             const float* __restrict__ w_ih0,
                             const float* __restrict__ w_ih12,
                             const float* __restrict__ w_hh,
                             const float* __restrict__ b_ih,
                             const float* __restrict__ b_hh,
                             Bank* __restrict__ ws) {
  int idx = blockIdx.x * 256 + threadIdx.x;   // grid covers TS_PAD*64 exactly
  int t = idx >> 6, lane = idx & 63;
  int row = lane >> 4, quad = (lane >> 2) & 3, tsl = lane & 3;
  int i = t - row;                            // cell this row handles at step t
  int g = tsl * 3 + (quad < 3 ? quad : 0);
  const float LOG2E = 1.4426950408889634f;
  const float sact = (tsl == 2) ? 2.0f * LOG2E : -LOG2E;
  float wi[4] = {0.f, 0.f, 0.f, 0.f}, wh[4] = {0.f, 0.f, 0.f, 0.f};
  float bias = 0.f;
  bool valid = (row < 3) && (quad < 3) && (i >= 0) && (i < NC);
  if (valid) {
    if (row == 0) {
      bias = w_ih0[i * 12 + g] * state[i];    // fold Wi*state into bias
    } else {
      const float* base = w_ih12 + ((size_t)(i * 2 + (row - 1)) * 12 + g) * 3;
#pragma unroll
      for (int k = 0; k < 4; ++k) {           // slot k feeds row_ror:4k source
        int qk = (quad - k) & 3;
        if (qk < 3) wi[k] = base[qk];
      }
    }
    const float* hb = w_hh + ((size_t)(i * 3 + row) * 12 + g) * 3;
#pragma unroll
    for (int k = 0; k < 4; ++k) {
      int qk = (quad - k) & 3;
      if (qk < 3) wh[k] = hb[qk];
    }
    bias += b_ih[(i * 3 + row) * 12 + g] + b_hh[(i * 3 + row) * 12 + g];
#pragma unroll
    for (int k = 0; k < 4; ++k) { wi[k] *= sact; wh[k] *= sact; }
    bias *= sact;                             // prescale: kills gate*sact mul
  }
  Bank bk;
  bk.a.x = wi[0]; bk.a.y = wi[1]; bk.a.z = wi[2]; bk.a.w = wi[3];
  bk.b.x = wh[0]; bk.b.y = wh[1]; bk.b.z = wh[2]; bk.b.w = wh[3];
  bk.c.x = bias;  bk.c.y = 0.f;
  ws[(size_t)t * 64 + lane] = bk;
}

// ---------------- main chain kernel: 1 wave --------------------------------
__global__ __launch_bounds__(64, 1) void lstm_fast(const Bank* __restrict__ ws,
                                                   float* __restrict__ out) {
  __shared__ float slog[2112];  // 8448 B: [0,3900) h stream, [4096,..) dump

  const int lane = threadIdx.x;
  const int row  = lane >> 4;     // 0:L0 1:L1 2:L2 3:dummy
  const int quad = (lane >> 2) & 3;
  const int tsl  = lane & 3;      // 0:i 1:f 2:g 3:o

  const float LOG2E = 1.4426950408889634f;
  // c is carried in the 2*log2e domain: vg is produced pre-scaled so that
  // cn' = 2*log2e*cn, letting tanh(c) use exp2(cn') with no mul on the chain.
  const float mact = (tsl == 2) ? (-4.0f * LOG2E) : 1.0f;
  const float nact = (tsl == 2) ? ( 2.0f * LOG2E) : 0.0f;
  const bool pickY = (lane >= 32) && (lane < 48);  // row2 takes y-result
  const bool outLane = (row == 2) && (tsl == 0) && (quad < 3);

  int sAddr = outLane ? quad * 4 : (4096 + lane * 4);  // byte addr into slog

  const char* sb = (const char*)ws;   // wave-uniform stream pointer (SALU)
  const int voff = lane * 48;         // per-lane constant byte offset
  float4 wa[6], wb[6];
  float  bs[6];
  float h = 0.f, c = 0.f;             // c in scaled domain (0 is 0 either way)

#pragma unroll
  for (int u = 0; u < 6; ++u) {
    wa[u] = *(const float4*)(sb + voff);
    wb[u] = *(const float4*)(sb + voff + 16);
    bs[u] = *(const float*)(sb + voff + 32);
    sb += 64 * sizeof(Bank);
  }

  for (int t = 0; t < TSTEPS; t += 6) {
#pragma unroll
    for (int u = 0; u < 6; ++u) {
      // ---- X route: rows [., h0, h1, .] via p32 -> p16swap -> 1 cndmask ----
      unsigned hv = __float_as_uint(h);
      uint2v p32 = __builtin_amdgcn_permlane32_swap(hv, hv, false, false);
      // p32.x rows = [h2, h3, h0, h1]
      uint2v s16 = __builtin_amdgcn_permlane16_swap(p32.x, hv, false, false);
      // s16.x rows = [h2, h0, h0, h2] ; s16.y rows = [h3, h1, h1, h3]
      float X = __uint_as_float(pickY ? s16.y : s16.x);
      // row0's X is garbage-but-finite: its wi are all zero (state folded).
      // ---- quad rotations (weights pre-permuted at staging) ----
      float H1 = rorf<0x124>(h), H2 = rorf<0x128>(h), H3 = rorf<0x12C>(h);
      float X1 = rorf<0x124>(X), X2 = rorf<0x128>(X), X3 = rorf<0x12C>(X);
      // ---- gate tree: H-side accumulates during the X route; X folds late --
      float cH = fmaf(wb[u].y, H1, fmaf(wb[u].x, h, bs[u]));
      cH       = fmaf(wb[u].z, H2, cH);
      cH       = fmaf(wb[u].w, H3, cH);
      float mA = fmaf(wa[u].x, X,  cH);
      float mB = fmaf(wa[u].z, X2, wa[u].y * X1);
      float gate = fmaf(wa[u].w, X3, mA) + mB;
      // ---- unified activation (dd = 1/(1+2^gate')) ----
      float aa  = fexp2(gate);
      float dd  = frcp(1.0f + aa);
      float act = fmaf(dd, mact, nact);   // sigmoid, or 2log2e * tanh (g lane)
      float vi = qb<0>(act), vf = qb<1>(act), vg = qb<2>(act), vo = qb<3>(act);
      float nvo2 = -2.0f * vo;            // off critical path
      float cn = fmaf(vf, c, vi * vg);    // scaled domain: cn' = 2log2e * cn
      float a2 = fexp2(cn);               // = e^{2c}, no mul needed
      float d2 = frcp(1.0f + a2);
      h = fmaf(d2, nvo2, vo);             // vo * tanh(c), fused
      c = cn;
      // zero-staged weights keep invalid/dummy lanes at h=c=0 exactly.
      *(float*)((char*)slog + sAddr + u * 12) = h;
      // ---- refill bank u for step t+u+6 (uniform base + const lane offset) -
      wa[u] = *(const float4*)(sb + voff);
      wb[u] = *(const float4*)(sb + voff + 16);
      bs[u] = *(const float*)(sb + voff + 32);
      sb += 64 * sizeof(Bank);
    }
    sAddr += 72;
  }

  __syncthreads();

  for (int ci = lane; ci < NC; ci += 64) {
    int s = (ci + 2) * 3;   // cell ci was stored at step ci+2
    float a0 = slog[s], a1 = slog[s + 1], a2v = slog[s + 2];
    float mx = fmaxf(fmaxf(a0, a1), a2v);
    float e0 = fexp2((a0 - mx) * LOG2E);
    float e1 = fexp2((a1 - mx) * LOG2E);
    float e2 = fexp2((a2v - mx) * LOG2E);
    float inv = frcp(e0 + e1 + e2);
    out[ci * 3 + 0] = e0 * inv;
    out[ci * 3 + 1] = e1 * inv;
    out[ci * 3 + 2] = e2 * inv;
  }
}

// ---------------- fallback: proven R1 kernel (used if ws too small) ----------
__global__ __launch_bounds__(64, 1) void lstm_chain_fb(
    const float* __restrict__ state, const float* __restrict__ w_ih0,
    const float* __restrict__ w_ih12, const float* __restrict__ w_hh,
    const float* __restrict__ b_ih, const float* __restrict__ b_hh,
    float* __restrict__ out) {
  __shared__ float slog[NC * 3];
  const int lane = threadIdx.x;
  const int row = lane >> 4, col = lane & 15, quad = col >> 2, tsl = col & 3;
  const int lc = row < 2 ? row : 2, jc = quad < 2 ? quad : 2;
  const int g = tsl * 3 + jc;
  const float LOG2E = 1.4426950408889634f;
  const float sact = (tsl == 2) ? 2.0f * LOG2E : -LOG2E;
  const float mact = (tsl == 2) ? -2.0f : 1.0f;
  const float nact = (tsl == 2) ? 1.0f : 0.0f;
  const int strideWi = (row == 0) ? 48 : 288;
  const int kWi = (row == 0) ? g * 4 : ((lc - 1) * 12 + g) * 12;
  const int kWh = (lc * 12 + g) * 12, kB = (lc * 12 + g) * 4;
  const char* wiBase = (row == 0) ? (const char*)w_ih0 : (const char*)w_ih12;
  const int ix0 = ((row - 1) * 16 + 0 + tsl) * 4, ix1 = ((row - 1) * 16 + 4 + tsl) * 4,
            ix2 = ((row - 1) * 16 + 8 + tsl) * 4;
  const int ih0 = (row * 16 + 0 + tsl) * 4, ih1 = (row * 16 + 4 + tsl) * 4,
            ih2 = (row * 16 + 8 + tsl) * 4;
  const bool isRow0 = (row == 0);
  const bool outLane = (row == 2) && (tsl == 0) && (quad < 3);
  float h = 0.f, c = 0.f;
  float Wi0[4], Wi1[4], Wi2[4], Wh0[4], Wh1[4], Wh2[4], Bs[4], St[4];
  auto prefetch = [&](int ts, int u) {
    int ip = ts - row; ip = ip < 0 ? 0 : (ip > NC - 1 ? NC - 1 : ip);
    const int oWi = ip * strideWi + kWi, oWh = ip * 432 + kWh, oB = ip * 144 + kB;
    float a0 = *(const float*)(wiBase + oWi);
    float a1 = *(const float*)(wiBase + oWi + 4);
    float a2 = *(const float*)(wiBase + oWi + 8);
    Wi0[u] = a0; Wi1[u] = isRow0 ? 0.f : a1; Wi2[u] = isRow0 ? 0.f : a2;
    Wh0[u] = *(const float*)((const char*)w_hh + oWh);
    Wh1[u] = *(const float*)((const char*)w_hh + oWh + 4);
    Wh2[u] = *(const float*)((const char*)w_hh + oWh + 8);
    Bs[u] = *(const float*)((const char*)b_ih + oB) + *(const float*)((const char*)b_hh + oB);
    int si = ts > NC - 1 ? NC - 1 : ts;
    St[u] = state[si];
  };
  auto stepf = [&](int t, int u) {
    float x0 = bperm(ix0, h), x1 = bperm(ix1, h), x2 = bperm(ix2, h);
    float p0 = bperm(ih0, h), p1 = bperm(ih1, h), p2 = bperm(ih2, h);
    x0 = isRow0 ? St[u] : x0; x1 = isRow0 ? 0.f : x1; x2 = isRow0 ? 0.f : x2;
    float gate = Bs[u] + Wi0[u] * x0 + Wi1[u] * x1 + Wi2[u] * x2 +
                 Wh0[u] * p0 + Wh1[u] * p1 + Wh2[u] * p2;
    float aa = fexp2(gate * sact);
    float act = fmaf(frcp(1.0f + aa), mact, nact);
    float vi = qb<0>(act), vf = qb<1>(act), vg = qb<2>(act), vo = qb<3>(act);
    float cn = fmaf(vf, c, vi * vg);
    float a2c = fexp2(cn * (2.0f * LOG2E));
    float th = fmaf(frcp(1.0f + a2c), -2.0f, 1.0f);
    float hn = vo * th;
    bool valid = (row < 3) && (t >= row) && ((t - row) < NC);
    h = valid ? hn : h; c = valid ? cn : c;
    if (outLane && valid) slog[(t - 2) * 3 + quad] = hn;
  };
#pragma unroll
  for (int u = 0; u < 4; ++u) prefetch(u, u);
  for (int t = 0; t < TSTEPS; t += 4) {
#pragma unroll
    for (int u = 0; u < 4; ++u) { stepf(t + u, u); prefetch(t + u + 4, u); }
  }
  __syncthreads();
  for (int ci = lane; ci < NC; ci += 64) {
    float a0 = slog[ci * 3], a1 = slog[ci * 3 + 1], a2v = slog[ci * 3 + 2];
    float mx = fmaxf(fmaxf(a0, a1), a2v);
    float e0 = fexp2((a0 - mx) * LOG2E), e1 = fexp2((a1 - mx) * LOG2E),
          e2 = fexp2((a2v - mx) * LOG2E);
    float inv = frcp(e0 + e1 + e2);
    out[ci * 3 + 0] = e0 * inv; out[ci * 3 + 1] = e1 * inv; out[ci * 3 + 2] = e2 * inv;
  }
}

extern "C" void kernel_launch(void* const* d_in, const int* in_sizes, int n_in,
                              void* d_out, int out_size, void* d_ws, size_t ws_size,
                              hipStream_t stream) {
  const float* state  = (const float*)d_in[0];
  const float* w_ih0  = (const float*)d_in[1];
  const float* w_ih12 = (const float*)d_in[2];
  const float* w_hh   = (const float*)d_in[3];
  const float* b_ih   = (const float*)d_in[4];
  const float* b_hh   = (const float*)d_in[5];
  float* out = (float*)d_out;
  const size_t need = sizeof(Bank) * (size_t)TS_PAD * 64;  // ~1.03 MB
  if (ws_size >= need) {
    Bank* ws = (Bank*)d_ws;
    hipLaunchKernelGGL(stage_kernel, dim3(TS_PAD * 64 / 256), dim3(256), 0, stream,
                       state, w_ih0, w_ih12, w_hh, b_ih, b_hh, ws);
    hipLaunchKernelGGL(lstm_fast, dim3(1), dim3(64), 0, stream, ws, out);
  } else {
    hipLaunchKernelGGL(lstm_chain_fb, dim3(1), dim3(64), 0, stream,
                       state, w_ih0, w_ih12, w_hh, b_ih, b_hh, out);
  }
}